// Round 22
// baseline (67.600 us; speedup 1.0000x reference)
//
#include <hip/hip_runtime.h>
#include <math.h>

#define N_NEU 256
#define D_DIM 32
#define KFD   16
#define KN    50
#define B_SZ  512
#define UINF  128
#define GAMMA 0.1f
#define DT    0.05f
#define NSTEP 20

// 4096-knot NEAREST-NEIGHBOR bf16 table, Delta = 1/32, range [-64, +64).
#define TBL_K   4096
#define TBL_LO  (-64.0f)
#define TBL_IDL 32.0f

#define TOPK_BLKS  N_NEU                 // 256
#define TBL_BLKS   (TBL_K * 16 / 256)    // 256 (packed: 16 u32 per knot)

typedef __attribute__((ext_vector_type(8))) short bf16x8;
typedef __attribute__((ext_vector_type(4))) float f32x4;

__device__ __forceinline__ unsigned short f2bf(float f) {
    unsigned u = __float_as_uint(f);
    u += 0x7FFFu + ((u >> 16) & 1u);     // round-to-nearest-even
    return (unsigned short)(u >> 16);
}
__device__ __forceinline__ float bf_lo(unsigned q) { return __uint_as_float(q << 16); }
__device__ __forceinline__ float bf_hi(unsigned q) { return __uint_as_float(q & 0xFFFF0000u); }

// ---------------------------------------------------------------------------
// Kernel A: topk [0,256) + packed-bf16 table [256,512).
// topk = rank-parallel selection (r20) + BANK-STAGGERED slot schedule (new):
// the wave-gather in steps reads, per instruction, slot c of all 64 lanes
// (16 neurons x 4 subthreads). Random assignment -> 64 iid banks -> ~4.2-way
// conflicts (measured ~900 cyc/CU-step). Instead: sort each neuron's 50
// neighbors by bank (second rank-count pass), then place bank-rank p at the
// slot with 14s + c == p - 13n (mod 56) (bijective; 13 coprime 56). Each
// column then reads quartile-staggered, neuron-rotated bank-quantiles ->
// near-uniform bank coverage. The 6 pads/neuron land on rotating columns and
// all point to a_sh[0] (same-address broadcast = free).
// Layouts consumed by steps: idxS[k*256+n] (k = s*14+c, all 56 valid),
// vals2T pair layout float2 [jj][n*4+s] elem p  <->  k = s*14 + 2jj + p.
// ---------------------------------------------------------------------------
__global__ __launch_bounds__(256) void pre_kernel(const float* __restrict__ features,
                                                  const float* __restrict__ sig_w1,
                                                  const float* __restrict__ sig_b1,
                                                  const float* __restrict__ sig_w2,
                                                  int* __restrict__ idxS,
                                                  float* __restrict__ vals2T,
                                                  unsigned int* __restrict__ tblb) {
    __shared__ float fsh[N_NEU][KFD + 1];
    __shared__ float sim_sh[N_NEU];
    __shared__ int   rank_sh[N_NEU];

    const int bid = blockIdx.x;

    if (bid < TOPK_BLKS) {
        // ---- topk ----
        const int n = bid;
        const int j = threadIdx.x;

        float v[KFD];
        float s = 0.f;
#pragma unroll
        for (int d = 0; d < KFD; ++d) { v[d] = features[j * KFD + d]; s = fmaf(v[d], v[d], s); }
        const float nrm = sqrtf(s);
#pragma unroll
        for (int d = 0; d < KFD; ++d) fsh[j][d] = v[d] / nrm;
        __syncthreads();

        float dot = 0.f;
#pragma unroll
        for (int d = 0; d < KFD; ++d) dot = fmaf(fsh[n][d], fsh[j][d], dot);
        sim_sh[j] = dot;
        __syncthreads();

        // pass 1: similarity rank (jax.lax.top_k order, lowest-index tiebreak)
        const float my = dot;
        int rank = 0;
#pragma unroll 8
        for (int i = 0; i < N_NEU; ++i) {
            const float si = sim_sh[i];
            rank += (si > my || (si == my && i < j)) ? 1 : 0;
        }
        rank_sh[j] = rank;
        __syncthreads();

        // pass 2: bank-rank among the selected set (sort by (j&31, j))
        if (rank < KN) {
            const int bj = j & 31;
            int brank = 0;
#pragma unroll 8
            for (int i = 0; i < N_NEU; ++i) {
                const bool sel = rank_sh[i] < KN;
                const int  bi  = i & 31;
                brank += (sel && (bi < bj || (bi == bj && i < j))) ? 1 : 0;
            }
            // staggered slot: 14*s + c = (brank - 13*n) mod 56
            const int q  = ((brank - 13 * n) % 56 + 56) % 56;
            const int s_ = q / 14;
            const int c_ = q - 14 * s_;
            idxS[q * N_NEU + n] = j;     // q == s_*14 + c_
            vals2T[((c_ >> 1) * 1024 + n * 4 + s_) * 2 + (c_ & 1)] = my;
        }
        // pads: bank-ranks 50..55 -> idx 0 (broadcast), val 0
        if (j < 6) {
            const int qp = ((50 + j - 13 * n) % 56 + 56) % 56;
            const int sp = qp / 14;
            const int cp = qp - 14 * sp;
            idxS[qp * N_NEU + n] = 0;
            vals2T[((cp >> 1) * 1024 + n * 4 + sp) * 2 + (cp & 1)] = 0.f;
        }
    } else {
        // ---- packed bf16 table: tblb[k*16+p] = bf16(DT*G_{2p}) | bf16(DT*G_{2p+1})<<16
        const int gid = (bid - TOPK_BLKS) * 256 + threadIdx.x;  // k*16+p
        const int k = gid >> 4, p = gid & 15;
        const int d0 = 2 * p, d1 = 2 * p + 1;
        const float s0 = TBL_LO + (float)k / TBL_IDL;
        float g0 = 0.f, g1 = 0.f;
#pragma unroll
        for (int j = 0; j < 16; ++j) {
            const float w1 = sig_w1[j], b1 = sig_b1[j];
            const float h0 = fmaf(s0, w1, b1);
            const float e0 = 0.5f * h0 * (1.0f + erff(h0 * 0.70710678118654752f));
            g0 = fmaf(e0, sig_w2[d0 * 16 + j], g0);
            g1 = fmaf(e0, sig_w2[d1 * 16 + j], g1);
        }
        g0 *= DT; g1 *= DT;
        tblb[gid] = (unsigned int)f2bf(g0) | ((unsigned int)f2bf(g1) << 16);
    }
}

// ---------------------------------------------------------------------------
// Kernel B: fused uproj-GEMM + 20-step recurrence (r21 structure, 59.9us).
// Only change: gather slots now come fully scheduled from idxS (all 56
// valid, bank-staggered; no k<KN guard).
// LDS = 8704 + 73728 + 2048 = 84480.
// ---------------------------------------------------------------------------
__global__ __launch_bounds__(1024) void steps_kernel(const float* __restrict__ u,
                                                     const float* __restrict__ w_in,
                                                     const float* __restrict__ b_in,
                                                     const float* __restrict__ bias,
                                                     const float* __restrict__ sig_b2,
                                                     const int* __restrict__ idxS,
                                                     const float* __restrict__ vals2T,
                                                     const unsigned int* __restrict__ tblb,
                                                     float* __restrict__ out) {
    __shared__ unsigned short wsh[32 * 136];       // bf16 w_in, row stride 136
    __shared__ float cdt_sh[2 * 256 * 36];         // 73728 B, row stride 36
    __shared__ unsigned int a_sh[2 * N_NEU];       // packed 2-batch bf16

    const int t = threadIdx.x;

    // ---- phase 0a: stage w_in -> LDS bf16 ----
    {
        const float4 w4 = reinterpret_cast<const float4*>(w_in)[t];
        const int d = t >> 5, k0 = (t & 31) * 4;
        unsigned short* wp = &wsh[d * 136 + k0];
        wp[0] = f2bf(w4.x); wp[1] = f2bf(w4.y); wp[2] = f2bf(w4.z); wp[3] = f2bf(w4.w);
    }
    __syncthreads();

    // ---- phase 0b: per-wave 32-row GEMM ----
    {
        const int wave = t >> 6;
        const int lane = t & 63;
        const int row  = lane & 15;
        const int kg   = lane >> 4;
        const int bb0  = wave >> 3;                    // which batch of the pair
        const int wrow = (wave & 7) * 32;              // first neuron row of wave
        const long bB  = (long)blockIdx.x * 2 + bb0;

        bf16x8 bfrag[2][4];
#pragma unroll
        for (int dt_ = 0; dt_ < 2; ++dt_)
#pragma unroll
            for (int kk = 0; kk < 4; ++kk)
                bfrag[dt_][kk] = *reinterpret_cast<const bf16x8*>(
                    &wsh[(dt_ * 16 + row) * 136 + kk * 32 + kg * 8]);

#pragma unroll
        for (int t4 = 0; t4 < 2; ++t4) {
            const float* ub = u + (bB * N_NEU + wrow + t4 * 16 + row) * UINF + kg * 8;
            float4 L[8];
#pragma unroll
            for (int kk = 0; kk < 4; ++kk) {
                L[kk * 2 + 0] = *reinterpret_cast<const float4*>(ub + kk * 32);
                L[kk * 2 + 1] = *reinterpret_cast<const float4*>(ub + kk * 32 + 4);
            }
            f32x4 a0 = {0.f, 0.f, 0.f, 0.f};
            f32x4 a1 = {0.f, 0.f, 0.f, 0.f};
#pragma unroll
            for (int kk = 0; kk < 4; ++kk) {
                bf16x8 af;
                const float4 x0 = L[kk * 2], x1 = L[kk * 2 + 1];
                af[0] = (short)f2bf(x0.x); af[1] = (short)f2bf(x0.y);
                af[2] = (short)f2bf(x0.z); af[3] = (short)f2bf(x0.w);
                af[4] = (short)f2bf(x1.x); af[5] = (short)f2bf(x1.y);
                af[6] = (short)f2bf(x1.z); af[7] = (short)f2bf(x1.w);
                a0 = __builtin_amdgcn_mfma_f32_16x16x32_bf16(af, bfrag[0][kk], a0, 0, 0, 0);
                a1 = __builtin_amdgcn_mfma_f32_16x16x32_bf16(af, bfrag[1][kk], a1, 0, 0, 0);
            }
            const int   d0   = row;
            const int   d1   = 16 + row;
            const float add0 = b_in[d0] + sig_b2[d0];
            const float add1 = b_in[d1] + sig_b2[d1];
#pragma unroll
            for (int r = 0; r < 4; ++r) {
                const int nl = wrow + t4 * 16 + kg * 4 + r;
                cdt_sh[bb0 * 9216 + nl * 36 + d0] = DT * (a0[r] + add0 + bias[nl * D_DIM + d0]);
                cdt_sh[bb0 * 9216 + nl * 36 + d1] = DT * (a1[r] + add1 + bias[nl * D_DIM + d1]);
            }
        }
    }
    __syncthreads();

    // ---- redistribute to per-thread ccdt regs ----
    const int n  = t >> 2;
    const int s  = t & 3;
    const int bb = s >> 1;
    const int h  = s & 1;
    const int b  = blockIdx.x * 2 + bb;

    float ccdt[16];
    {
        const float* cbase = &cdt_sh[bb * 9216 + n * 36 + h * 16];
#pragma unroll
        for (int i = 0; i < 4; ++i) {
            const float4 cv = *reinterpret_cast<const float4*>(cbase + i * 4);
            ccdt[4 * i + 0] = cv.x; ccdt[4 * i + 1] = cv.y;
            ccdt[4 * i + 2] = cv.z; ccdt[4 * i + 3] = cv.w;
        }
    }

    // ---- step-invariant per-thread vals + gather pointers (scheduled) ----
    const float2* v2g = reinterpret_cast<const float2*>(vals2T);
    float2 vv[7];
#pragma unroll
    for (int jj = 0; jj < 7; ++jj) vv[jj] = v2g[jj * 1024 + t];

    const unsigned int* gp[14];
#pragma unroll
    for (int j = 0; j < 14; ++j) {
        const int ii = idxS[(s * 14 + j) * N_NEU + n];
        gp[j] = &a_sh[ii];
    }

    float x[16];
#pragma unroll
    for (int d = 0; d < 16; ++d) x[d] = 0.f;

    const float K1 = 1.0f - DT * GAMMA;      // 0.995
    const float L2E2 = 2.8853900817779268f;  // 2*log2(e)

#define STEP_BODY(BUF)                                                          \
    {                                                                           \
        float nh0 = 0.f, nh1 = 0.f;                                             \
        _Pragma("unroll")                                                       \
        for (int d = 0; d < 16; d += 2) {                                       \
            nh0 = fmaf(x[d], x[d], nh0);                                        \
            nh1 = fmaf(x[d + 1], x[d + 1], nh1);                                \
        }                                                                       \
        const float nh = nh0 + nh1;                                             \
        const float nfull = nh + __shfl_xor(nh, 1, 64) + 1e-12f;                \
        const float z = sqrtf(nfull);                                           \
        const float e2 = __builtin_amdgcn_exp2f(L2E2 * z);                      \
        const float a = fmaf(-2.0f, __builtin_amdgcn_rcpf(e2 + 1.0f), 1.0f);    \
        const float ao = __shfl_xor(a, 2, 64);                                  \
        if (s == 0) a_sh[(BUF) * N_NEU + n] = (unsigned int)f2bf(a) | ((unsigned int)f2bf(ao) << 16); \
        _Pragma("unroll")                                                       \
        for (int d = 0; d < 16; ++d) x[d] = fmaf(K1, x[d], ccdt[d]);            \
        __syncthreads();                                                        \
        float sA0 = 0.f, sA1 = 0.f, sB0 = 0.f, sB1 = 0.f;                       \
        _Pragma("unroll")                                                       \
        for (int jj = 0; jj < 7; ++jj) {                                        \
            const unsigned int p0 = gp[2 * jj][(BUF) * N_NEU];                  \
            const unsigned int p1 = gp[2 * jj + 1][(BUF) * N_NEU];              \
            sA0 = fmaf(bf_lo(p0), vv[jj].x, sA0);                               \
            sB0 = fmaf(bf_hi(p0), vv[jj].x, sB0);                               \
            sA1 = fmaf(bf_lo(p1), vv[jj].y, sA1);                               \
            sB1 = fmaf(bf_hi(p1), vv[jj].y, sB1);                               \
        }                                                                       \
        float sA = sA0 + sA1;                                                   \
        float sB = sB0 + sB1;                                                   \
        sA += __shfl_xor(sA, 1, 64); sA += __shfl_xor(sA, 2, 64);               \
        sB += __shfl_xor(sB, 1, 64); sB += __shfl_xor(sB, 2, 64);               \
        const float syn = bb ? sB : sA;                                         \
        const float uu = fmaf(syn, TBL_IDL, 0.5f - TBL_LO * TBL_IDL);           \
        int i = (int)uu;   /* nearest knot */                                   \
        i = (i < 0) ? 0 : (i > TBL_K - 1 ? TBL_K - 1 : i);                      \
        const uint4* rp = reinterpret_cast<const uint4*>(tblb + (size_t)i * 16 + h * 8); \
        _Pragma("unroll")                                                       \
        for (int c = 0; c < 2; ++c) {                                           \
            const uint4 q = rp[c];                                              \
            x[8 * c + 0] += bf_lo(q.x);                                         \
            x[8 * c + 1] += bf_hi(q.x);                                         \
            x[8 * c + 2] += bf_lo(q.y);                                         \
            x[8 * c + 3] += bf_hi(q.y);                                         \
            x[8 * c + 4] += bf_lo(q.z);                                         \
            x[8 * c + 5] += bf_hi(q.z);                                         \
            x[8 * c + 6] += bf_lo(q.w);                                         \
            x[8 * c + 7] += bf_hi(q.w);                                         \
        }                                                                       \
    }

    for (int it = 0; it < NSTEP / 2; ++it) {
        STEP_BODY(0);
        STEP_BODY(1);
    }
#undef STEP_BODY

    float4* op4 = reinterpret_cast<float4*>(out + ((size_t)b * N_NEU + n) * D_DIM + h * 16);
#pragma unroll
    for (int i = 0; i < 4; ++i)
        op4[i] = make_float4(x[4 * i + 0], x[4 * i + 1], x[4 * i + 2], x[4 * i + 3]);
}

extern "C" void kernel_launch(void* const* d_in, const int* in_sizes, int n_in,
                              void* d_out, int out_size, void* d_ws, size_t ws_size,
                              hipStream_t stream) {
    const float* u        = (const float*)d_in[0];
    const float* features = (const float*)d_in[1];
    const float* bias     = (const float*)d_in[2];
    const float* w_in     = (const float*)d_in[3];
    const float* b_in     = (const float*)d_in[4];
    const float* sig_w1   = (const float*)d_in[5];
    const float* sig_b1   = (const float*)d_in[6];
    const float* sig_w2   = (const float*)d_in[7];
    const float* sig_b2   = (const float*)d_in[8];
    float* out = (float*)d_out;

    char*         ws     = (char*)d_ws;
    int*          idxS   = (int*)ws;                      // 56*256*4 = 57344 B
    float*        vals2T = (float*)(ws + 57344);          // 57344 B
    unsigned int* tblb   = (unsigned int*)(ws + 114688);  // 262144 B

    hipLaunchKernelGGL(pre_kernel, dim3(TOPK_BLKS + TBL_BLKS), dim3(256), 0, stream,
                       features, sig_w1, sig_b1, sig_w2, idxS, vals2T, tblb);
    hipLaunchKernelGGL(steps_kernel, dim3(B_SZ / 2), dim3(1024), 0, stream,
                       u, w_in, b_in, bias, sig_b2, idxS, vals2T, tblb, out);
}

// Round 23
// 59.992 us; speedup vs baseline: 1.1268x; 1.1268x over previous
//
#include <hip/hip_runtime.h>
#include <math.h>

#define N_NEU 256
#define D_DIM 32
#define KFD   16
#define KN    50
#define B_SZ  512
#define UINF  128
#define GAMMA 0.1f
#define DT    0.05f
#define NSTEP 20

// 4096-knot NEAREST-NEIGHBOR bf16 table, Delta = 1/32, range [-64, +64).
// NN err ~9e-4/step + bf16 quant ~1e-4/step -> <=0.03 accumulated (budget 0.196).
#define TBL_K   4096
#define TBL_LO  (-64.0f)
#define TBL_IDL 32.0f

#define TOPK_BLKS  N_NEU                 // 256
#define TBL_BLKS   (TBL_K * 16 / 256)    // 256 (packed: 16 u32 per knot)

typedef __attribute__((ext_vector_type(8))) short bf16x8;
typedef __attribute__((ext_vector_type(4))) float f32x4;

__device__ __forceinline__ unsigned short f2bf(float f) {
    unsigned u = __float_as_uint(f);
    u += 0x7FFFu + ((u >> 16) & 1u);     // round-to-nearest-even
    return (unsigned short)(u >> 16);
}
__device__ __forceinline__ float bf_lo(unsigned q) { return __uint_as_float(q << 16); }
__device__ __forceinline__ float bf_hi(unsigned q) { return __uint_as_float(q & 0xFFFF0000u); }

// ---------------------------------------------------------------------------
// Kernel A: topk [0,256) + packed-bf16 table [256,512).
// topk via rank-parallel selection (r20, verified): element j's output
// position = #{i : sim[i]>sim[j] || (sim[i]==sim[j] && i<j)} — equals
// jax.lax.top_k descending order with lowest-index tie-break.
// vals ZERO-PADDED to 56 in pair layout float2 [jj][n*4+s], jj<7,
// covering k = s*14 + 2*jj + p.
// ---------------------------------------------------------------------------
__global__ __launch_bounds__(256) void pre_kernel(const float* __restrict__ features,
                                                  const float* __restrict__ sig_w1,
                                                  const float* __restrict__ sig_b1,
                                                  const float* __restrict__ sig_w2,
                                                  int* __restrict__ idxT,
                                                  float* __restrict__ vals2T,
                                                  unsigned int* __restrict__ tblb) {
    __shared__ float fsh[N_NEU][KFD + 1];
    __shared__ float sim_sh[N_NEU];

    const int bid = blockIdx.x;

    if (bid < TOPK_BLKS) {
        // ---- topk ----
        const int n = bid;
        const int j = threadIdx.x;

        float v[KFD];
        float s = 0.f;
#pragma unroll
        for (int d = 0; d < KFD; ++d) { v[d] = features[j * KFD + d]; s = fmaf(v[d], v[d], s); }
        const float nrm = sqrtf(s);
#pragma unroll
        for (int d = 0; d < KFD; ++d) fsh[j][d] = v[d] / nrm;
        __syncthreads();

        float dot = 0.f;
#pragma unroll
        for (int d = 0; d < KFD; ++d) dot = fmaf(fsh[n][d], fsh[j][d], dot);
        sim_sh[j] = dot;
        __syncthreads();

        const float my = dot;
        int rank = 0;
#pragma unroll 8
        for (int i = 0; i < N_NEU; ++i) {
            const float si = sim_sh[i];
            rank += (si > my || (si == my && i < j)) ? 1 : 0;
        }
        if (rank < KN) {
            const int s_ = rank / 14;
            const int r_ = rank - 14 * s_;
            vals2T[((r_ >> 1) * 1024 + n * 4 + s_) * 2 + (r_ & 1)] = my;
            idxT[rank * N_NEU + n] = j;
        }
        if (j == 0) {   // zero-pad k = 50..55 (subthread 3, r = 8..13)
#pragma unroll
            for (int k = 50; k < 56; ++k) {
                const int r_ = k - 42;
                vals2T[((r_ >> 1) * 1024 + n * 4 + 3) * 2 + (r_ & 1)] = 0.f;
            }
        }
    } else {
        // ---- packed bf16 table: tblb[k*16+p] = bf16(DT*G_{2p}) | bf16(DT*G_{2p+1})<<16
        const int gid = (bid - TOPK_BLKS) * 256 + threadIdx.x;  // k*16+p
        const int k = gid >> 4, p = gid & 15;
        const int d0 = 2 * p, d1 = 2 * p + 1;
        const float s0 = TBL_LO + (float)k / TBL_IDL;
        float g0 = 0.f, g1 = 0.f;
#pragma unroll
        for (int j = 0; j < 16; ++j) {
            const float w1 = sig_w1[j], b1 = sig_b1[j];
            const float h0 = fmaf(s0, w1, b1);
            const float e0 = 0.5f * h0 * (1.0f + erff(h0 * 0.70710678118654752f));
            g0 = fmaf(e0, sig_w2[d0 * 16 + j], g0);
            g1 = fmaf(e0, sig_w2[d1 * 16 + j], g1);
        }
        g0 *= DT; g1 *= DT;
        tblb[gid] = (unsigned int)f2bf(g0) | ((unsigned int)f2bf(g1) << 16);
    }
}

// ---------------------------------------------------------------------------
// Kernel B: fused uproj-GEMM + 20-step recurrence (r21 configuration —
// best measured total 59.9us). Packed-bf16 NN table (2 uint4 loads =
// 32B/thread/step); packed 2-batch bf16 gather; one barrier/step.
// LDS = 8704 + 73728 + 2048 = 84480.
// ---------------------------------------------------------------------------
__global__ __launch_bounds__(1024) void steps_kernel(const float* __restrict__ u,
                                                     const float* __restrict__ w_in,
                                                     const float* __restrict__ b_in,
                                                     const float* __restrict__ bias,
                                                     const float* __restrict__ sig_b2,
                                                     const int* __restrict__ idxT,
                                                     const float* __restrict__ vals2T,
                                                     const unsigned int* __restrict__ tblb,
                                                     float* __restrict__ out) {
    __shared__ unsigned short wsh[32 * 136];       // bf16 w_in, row stride 136
    __shared__ float cdt_sh[2 * 256 * 36];         // 73728 B, row stride 36
    __shared__ unsigned int a_sh[2 * N_NEU];       // packed 2-batch bf16

    const int t = threadIdx.x;

    // ---- phase 0a: stage w_in -> LDS bf16 ----
    {
        const float4 w4 = reinterpret_cast<const float4*>(w_in)[t];
        const int d = t >> 5, k0 = (t & 31) * 4;
        unsigned short* wp = &wsh[d * 136 + k0];
        wp[0] = f2bf(w4.x); wp[1] = f2bf(w4.y); wp[2] = f2bf(w4.z); wp[3] = f2bf(w4.w);
    }
    __syncthreads();

    // ---- phase 0b: per-wave 32-row GEMM ----
    {
        const int wave = t >> 6;
        const int lane = t & 63;
        const int row  = lane & 15;
        const int kg   = lane >> 4;
        const int bb0  = wave >> 3;                    // which batch of the pair
        const int wrow = (wave & 7) * 32;              // first neuron row of wave
        const long bB  = (long)blockIdx.x * 2 + bb0;

        bf16x8 bfrag[2][4];
#pragma unroll
        for (int dt_ = 0; dt_ < 2; ++dt_)
#pragma unroll
            for (int kk = 0; kk < 4; ++kk)
                bfrag[dt_][kk] = *reinterpret_cast<const bf16x8*>(
                    &wsh[(dt_ * 16 + row) * 136 + kk * 32 + kg * 8]);

#pragma unroll
        for (int t4 = 0; t4 < 2; ++t4) {
            const float* ub = u + (bB * N_NEU + wrow + t4 * 16 + row) * UINF + kg * 8;
            float4 L[8];
#pragma unroll
            for (int kk = 0; kk < 4; ++kk) {
                L[kk * 2 + 0] = *reinterpret_cast<const float4*>(ub + kk * 32);
                L[kk * 2 + 1] = *reinterpret_cast<const float4*>(ub + kk * 32 + 4);
            }
            f32x4 a0 = {0.f, 0.f, 0.f, 0.f};
            f32x4 a1 = {0.f, 0.f, 0.f, 0.f};
#pragma unroll
            for (int kk = 0; kk < 4; ++kk) {
                bf16x8 af;
                const float4 x0 = L[kk * 2], x1 = L[kk * 2 + 1];
                af[0] = (short)f2bf(x0.x); af[1] = (short)f2bf(x0.y);
                af[2] = (short)f2bf(x0.z); af[3] = (short)f2bf(x0.w);
                af[4] = (short)f2bf(x1.x); af[5] = (short)f2bf(x1.y);
                af[6] = (short)f2bf(x1.z); af[7] = (short)f2bf(x1.w);
                a0 = __builtin_amdgcn_mfma_f32_16x16x32_bf16(af, bfrag[0][kk], a0, 0, 0, 0);
                a1 = __builtin_amdgcn_mfma_f32_16x16x32_bf16(af, bfrag[1][kk], a1, 0, 0, 0);
            }
            const int   d0   = row;
            const int   d1   = 16 + row;
            const float add0 = b_in[d0] + sig_b2[d0];
            const float add1 = b_in[d1] + sig_b2[d1];
#pragma unroll
            for (int r = 0; r < 4; ++r) {
                const int nl = wrow + t4 * 16 + kg * 4 + r;
                cdt_sh[bb0 * 9216 + nl * 36 + d0] = DT * (a0[r] + add0 + bias[nl * D_DIM + d0]);
                cdt_sh[bb0 * 9216 + nl * 36 + d1] = DT * (a1[r] + add1 + bias[nl * D_DIM + d1]);
            }
        }
    }
    __syncthreads();

    // ---- redistribute to per-thread ccdt regs ----
    const int n  = t >> 2;
    const int s  = t & 3;
    const int bb = s >> 1;
    const int h  = s & 1;
    const int b  = blockIdx.x * 2 + bb;

    float ccdt[16];
    {
        const float* cbase = &cdt_sh[bb * 9216 + n * 36 + h * 16];
#pragma unroll
        for (int i = 0; i < 4; ++i) {
            const float4 cv = *reinterpret_cast<const float4*>(cbase + i * 4);
            ccdt[4 * i + 0] = cv.x; ccdt[4 * i + 1] = cv.y;
            ccdt[4 * i + 2] = cv.z; ccdt[4 * i + 3] = cv.w;
        }
    }

    // ---- step-invariant per-thread vals + gather pointers ----
    const float2* v2g = reinterpret_cast<const float2*>(vals2T);
    float2 vv[7];
#pragma unroll
    for (int jj = 0; jj < 7; ++jj) vv[jj] = v2g[jj * 1024 + t];

    const unsigned int* gp[14];
#pragma unroll
    for (int j = 0; j < 14; ++j) {
        const int k = s * 14 + j;
        const int ii = (k < KN) ? idxT[k * N_NEU + n] : 0;
        gp[j] = &a_sh[ii];
    }

    float x[16];
#pragma unroll
    for (int d = 0; d < 16; ++d) x[d] = 0.f;

    const float K1 = 1.0f - DT * GAMMA;      // 0.995
    const float L2E2 = 2.8853900817779268f;  // 2*log2(e)

#define STEP_BODY(BUF)                                                          \
    {                                                                           \
        float nh0 = 0.f, nh1 = 0.f;                                             \
        _Pragma("unroll")                                                       \
        for (int d = 0; d < 16; d += 2) {                                       \
            nh0 = fmaf(x[d], x[d], nh0);                                        \
            nh1 = fmaf(x[d + 1], x[d + 1], nh1);                                \
        }                                                                       \
        const float nh = nh0 + nh1;                                             \
        const float nfull = nh + __shfl_xor(nh, 1, 64) + 1e-12f;                \
        const float z = sqrtf(nfull);                                           \
        const float e2 = __builtin_amdgcn_exp2f(L2E2 * z);                      \
        const float a = fmaf(-2.0f, __builtin_amdgcn_rcpf(e2 + 1.0f), 1.0f);    \
        const float ao = __shfl_xor(a, 2, 64);                                  \
        if (s == 0) a_sh[(BUF) * N_NEU + n] = (unsigned int)f2bf(a) | ((unsigned int)f2bf(ao) << 16); \
        _Pragma("unroll")                                                       \
        for (int d = 0; d < 16; ++d) x[d] = fmaf(K1, x[d], ccdt[d]);            \
        __syncthreads();                                                        \
        float sA0 = 0.f, sA1 = 0.f, sB0 = 0.f, sB1 = 0.f;                       \
        _Pragma("unroll")                                                       \
        for (int jj = 0; jj < 7; ++jj) {                                        \
            const unsigned int p0 = gp[2 * jj][(BUF) * N_NEU];                  \
            const unsigned int p1 = gp[2 * jj + 1][(BUF) * N_NEU];              \
            sA0 = fmaf(bf_lo(p0), vv[jj].x, sA0);                               \
            sB0 = fmaf(bf_hi(p0), vv[jj].x, sB0);                               \
            sA1 = fmaf(bf_lo(p1), vv[jj].y, sA1);                               \
            sB1 = fmaf(bf_hi(p1), vv[jj].y, sB1);                               \
        }                                                                       \
        float sA = sA0 + sA1;                                                   \
        float sB = sB0 + sB1;                                                   \
        sA += __shfl_xor(sA, 1, 64); sA += __shfl_xor(sA, 2, 64);               \
        sB += __shfl_xor(sB, 1, 64); sB += __shfl_xor(sB, 2, 64);               \
        const float syn = bb ? sB : sA;                                         \
        const float uu = fmaf(syn, TBL_IDL, 0.5f - TBL_LO * TBL_IDL);           \
        int i = (int)uu;   /* nearest knot */                                   \
        i = (i < 0) ? 0 : (i > TBL_K - 1 ? TBL_K - 1 : i);                      \
        const uint4* rp = reinterpret_cast<const uint4*>(tblb + (size_t)i * 16 + h * 8); \
        _Pragma("unroll")                                                       \
        for (int c = 0; c < 2; ++c) {                                           \
            const uint4 q = rp[c];                                              \
            x[8 * c + 0] += bf_lo(q.x);                                         \
            x[8 * c + 1] += bf_hi(q.x);                                         \
            x[8 * c + 2] += bf_lo(q.y);                                         \
            x[8 * c + 3] += bf_hi(q.y);                                         \
            x[8 * c + 4] += bf_lo(q.z);                                         \
            x[8 * c + 5] += bf_hi(q.z);                                         \
            x[8 * c + 6] += bf_lo(q.w);                                         \
            x[8 * c + 7] += bf_hi(q.w);                                         \
        }                                                                       \
    }

    for (int it = 0; it < NSTEP / 2; ++it) {
        STEP_BODY(0);
        STEP_BODY(1);
    }
#undef STEP_BODY

    float4* op4 = reinterpret_cast<float4*>(out + ((size_t)b * N_NEU + n) * D_DIM + h * 16);
#pragma unroll
    for (int i = 0; i < 4; ++i)
        op4[i] = make_float4(x[4 * i + 0], x[4 * i + 1], x[4 * i + 2], x[4 * i + 3]);
}

extern "C" void kernel_launch(void* const* d_in, const int* in_sizes, int n_in,
                              void* d_out, int out_size, void* d_ws, size_t ws_size,
                              hipStream_t stream) {
    const float* u        = (const float*)d_in[0];
    const float* features = (const float*)d_in[1];
    const float* bias     = (const float*)d_in[2];
    const float* w_in     = (const float*)d_in[3];
    const float* b_in     = (const float*)d_in[4];
    const float* sig_w1   = (const float*)d_in[5];
    const float* sig_b1   = (const float*)d_in[6];
    const float* sig_w2   = (const float*)d_in[7];
    const float* sig_b2   = (const float*)d_in[8];
    float* out = (float*)d_out;

    char*         ws     = (char*)d_ws;
    int*          idxT   = (int*)ws;                      // 51200 B
    float*        vals2T = (float*)(ws + 51200);          // 57344 B
    unsigned int* tblb   = (unsigned int*)(ws + 108544);  // 4096*16*4 = 262144 B

    hipLaunchKernelGGL(pre_kernel, dim3(TOPK_BLKS + TBL_BLKS), dim3(256), 0, stream,
                       features, sig_w1, sig_b1, sig_w2, idxT, vals2T, tblb);
    hipLaunchKernelGGL(steps_kernel, dim3(B_SZ / 2), dim3(1024), 0, stream,
                       u, w_in, b_in, bias, sig_b2, idxT, vals2T, tblb, out);
}